// Round 1
// baseline (1586.941 us; speedup 1.0000x reference)
//
#include <hip/hip_runtime.h>

// Problem constants
#define NV 65536     // flattened vectors (64*32*32)
#define KN 1024      // codebook size
#define DD 256       // embedding dim
#define DECAY_F 0.99f
#define OMD_F (1.0f - 0.99f)
#define EPS_F 1e-5f

// ---------------------------------------------------------------------------
// Kernel 1: eSq[k] = ||embedding[k]||^2. One wave per row (4 waves/block).
// ---------------------------------------------------------------------------
__global__ __launch_bounds__(256) void esq_kernel(const float* __restrict__ emb,
                                                  float* __restrict__ eSq) {
  const int lane = threadIdx.x & 63;
  const int row = blockIdx.x * 4 + (threadIdx.x >> 6);
  const float4 v = *(const float4*)(emb + row * DD + lane * 4);
  float s = v.x * v.x + v.y * v.y + v.z * v.z + v.w * v.w;
  #pragma unroll
  for (int off = 32; off > 0; off >>= 1) s += __shfl_down(s, off, 64);
  if (lane == 0) eSq[row] = s;
}

// ---------------------------------------------------------------------------
// Kernel 2: fused distance + argmin.
// Block: 256 threads handles 64 n-rows. k loop in 4 chunks of 256.
// Thread (ty,tx): ty=tid>>4 owns 4 n's, tx=tid&15 owns 16 k's of the chunk.
// dist = ||e||^2 - 2 x.e  (||x||^2 constant per n, irrelevant for argmin).
// First-index tie-break to match jnp.argmin.
// ---------------------------------------------------------------------------
__global__ __launch_bounds__(256) void argmin_kernel(
    const float* __restrict__ x, const float* __restrict__ emb,
    const float* __restrict__ eSq, int* __restrict__ idxOut) {
  __shared__ float xs[16][64];    // [d][n]   4 KiB
  __shared__ float es[16][256];   // [d][k]  16 KiB
  __shared__ float sdist[64][16]; //          4 KiB
  __shared__ int   sidx[64][16];  //          4 KiB

  const int tid = threadIdx.x;
  const int tx = tid & 15;
  const int ty = tid >> 4;
  const int nBase = blockIdx.x * 64;

  // loader mapping: 64 rows x 16 d per tile, float4 per thread
  const int ln = tid >> 2;        // 0..63
  const int ld = (tid & 3) * 4;   // 0,4,8,12

  float bestD[4];
  int bestK[4];
  #pragma unroll
  for (int i = 0; i < 4; i++) { bestD[i] = 3.4e38f; bestK[i] = 0; }

  for (int kc = 0; kc < 4; kc++) {
    float acc[4][16];
    #pragma unroll
    for (int i = 0; i < 4; i++)
      #pragma unroll
      for (int j = 0; j < 16; j++) acc[i][j] = 0.0f;

    for (int dc = 0; dc < 16; dc++) {
      const int d0 = dc * 16;
      // global loads into regs
      const float4 xv = *(const float4*)(x + (nBase + ln) * DD + d0 + ld);
      float4 ev[4];
      #pragma unroll
      for (int p = 0; p < 4; p++)
        ev[p] = *(const float4*)(emb + (kc * 256 + p * 64 + ln) * DD + d0 + ld);

      __syncthreads();  // previous tile fully consumed
      {
        float xa[4] = {xv.x, xv.y, xv.z, xv.w};
        #pragma unroll
        for (int j = 0; j < 4; j++) xs[ld + j][ln] = xa[j];
        #pragma unroll
        for (int p = 0; p < 4; p++) {
          float ea[4] = {ev[p].x, ev[p].y, ev[p].z, ev[p].w};
          #pragma unroll
          for (int j = 0; j < 4; j++) es[ld + j][p * 64 + ln] = ea[j];
        }
      }
      __syncthreads();  // tile ready

      #pragma unroll
      for (int d = 0; d < 16; d++) {
        const float4 xr = *(const float4*)&xs[d][ty * 4];
        const float4 e0 = *(const float4*)&es[d][tx * 16 + 0];
        const float4 e1 = *(const float4*)&es[d][tx * 16 + 4];
        const float4 e2 = *(const float4*)&es[d][tx * 16 + 8];
        const float4 e3 = *(const float4*)&es[d][tx * 16 + 12];
        const float xa[4] = {xr.x, xr.y, xr.z, xr.w};
        const float eb[16] = {e0.x, e0.y, e0.z, e0.w, e1.x, e1.y, e1.z, e1.w,
                              e2.x, e2.y, e2.z, e2.w, e3.x, e3.y, e3.z, e3.w};
        #pragma unroll
        for (int i = 0; i < 4; i++)
          #pragma unroll
          for (int j = 0; j < 16; j++) acc[i][j] += xa[i] * eb[j];
      }
    }

    // fold this k-chunk into running argmin (k ascending -> strict < keeps first)
    #pragma unroll
    for (int j = 0; j < 16; j++) {
      const int k = kc * 256 + tx * 16 + j;
      const float es2 = eSq[k];
      #pragma unroll
      for (int i = 0; i < 4; i++) {
        const float dist = es2 - 2.0f * acc[i][j];
        if (dist < bestD[i]) { bestD[i] = dist; bestK[i] = k; }
      }
    }
  }

  __syncthreads();
  #pragma unroll
  for (int i = 0; i < 4; i++) {
    sdist[ty * 4 + i][tx] = bestD[i];
    sidx[ty * 4 + i][tx] = bestK[i];
  }
  __syncthreads();
  if (tid < 64) {
    float bd = sdist[tid][0];
    int bk = sidx[tid][0];
    #pragma unroll
    for (int t = 1; t < 16; t++) {
      const float d = sdist[tid][t];
      const int k2 = sidx[tid][t];
      if (d < bd || (d == bd && k2 < bk)) { bd = d; bk = k2; }
    }
    idxOut[nBase + tid] = bk;
  }
}

// ---------------------------------------------------------------------------
// Kernel 3: gather quantized, codes, SSE, counts histogram, dw scatter-add.
// One wave per vector (4 waves / block).
// ---------------------------------------------------------------------------
__global__ __launch_bounds__(256) void gather_kernel(
    const float* __restrict__ x, const float* __restrict__ emb,
    const int* __restrict__ idx, float* __restrict__ outQ,
    float* __restrict__ outCodes, float* __restrict__ counts,
    float* __restrict__ dw, float* __restrict__ sse) {
  const int lane = threadIdx.x & 63;
  const int n = blockIdx.x * 4 + (threadIdx.x >> 6);
  const int k = idx[n];

  const float4 xv = *(const float4*)(x + n * DD + lane * 4);
  const float4 ev = *(const float4*)(emb + k * DD + lane * 4);
  *(float4*)(outQ + n * DD + lane * 4) = ev;

  const float d0 = ev.x - xv.x, d1 = ev.y - xv.y, d2 = ev.z - xv.z, d3 = ev.w - xv.w;
  float s = d0 * d0 + d1 * d1 + d2 * d2 + d3 * d3;

  float* dwp = dw + k * DD + lane * 4;
  atomicAdd(dwp + 0, xv.x);
  atomicAdd(dwp + 1, xv.y);
  atomicAdd(dwp + 2, xv.z);
  atomicAdd(dwp + 3, xv.w);

  #pragma unroll
  for (int off = 32; off > 0; off >>= 1) s += __shfl_down(s, off, 64);
  if (lane == 0) {
    atomicAdd(sse, s);
    atomicAdd(&counts[k], 1.0f);
    outCodes[n] = (float)k;
  }
}

// ---------------------------------------------------------------------------
// Kernel 4a: new_cluster_size, n-sum, normalized, losses. Single 1024 block.
// ---------------------------------------------------------------------------
__global__ __launch_bounds__(1024) void finalize1(
    const float* __restrict__ ema_cs, const float* __restrict__ counts,
    const float* __restrict__ sse, float* __restrict__ norm,
    float* __restrict__ outCS, float* __restrict__ outLoss) {
  __shared__ float red[1024];
  const int t = threadIdx.x;
  const float ncs = DECAY_F * ema_cs[t] + OMD_F * counts[t];
  outCS[t] = ncs;
  red[t] = ncs;
  __syncthreads();
  #pragma unroll
  for (int s = 512; s > 0; s >>= 1) {
    if (t < s) red[t] += red[t + s];
    __syncthreads();
  }
  const float n = red[0];
  norm[t] = (ncs + EPS_F) / (n + (float)KN * EPS_F) * n;
  if (t == 0) {
    const float mse = sse[0] * (1.0f / 16777216.0f);
    outLoss[0] = 0.25f * mse;  // commitment
    outLoss[1] = mse;          // codebook
  }
}

// ---------------------------------------------------------------------------
// Kernel 4b: new_ema_w and new_embedding.
// ---------------------------------------------------------------------------
__global__ __launch_bounds__(256) void finalize2(
    const float* __restrict__ ema_w, const float* __restrict__ dw,
    const float* __restrict__ norm, float* __restrict__ outEmb,
    float* __restrict__ outW) {
  const int i = blockIdx.x * 256 + threadIdx.x;  // 0..262143
  const float nw = DECAY_F * ema_w[i] + OMD_F * dw[i];
  outW[i] = nw;
  outEmb[i] = nw / norm[i >> 8];
}

// ---------------------------------------------------------------------------
extern "C" void kernel_launch(void* const* d_in, const int* in_sizes, int n_in,
                              void* d_out, int out_size, void* d_ws, size_t ws_size,
                              hipStream_t stream) {
  const float* x = (const float*)d_in[0];        // [65536, 256]
  const float* emb = (const float*)d_in[1];      // [1024, 256]
  const float* ema_cs = (const float*)d_in[2];   // [1024]
  const float* ema_w = (const float*)d_in[3];    // [1024, 256]
  float* out = (float*)d_out;
  float* ws = (float*)d_ws;

  // workspace layout (float offsets)
  float* eSq = ws + 0;                 // 1024
  int* idxBuf = (int*)(ws + 1024);     // 65536 ints
  float* counts = ws + 66560;          // 1024   (zeroed)
  float* dw = ws + 67584;              // 262144 (zeroed)
  float* sse = ws + 329728;            // 1      (zeroed)
  float* norm = ws + 329729;           // 1024

  // output layout (return-order flat, all fp32)
  float* outQ = out;                   // 16777216  quantized_st
  float* outCodes = out + 16777216;    // 65536     codes (as float)
  float* outLoss = out + 16842752;     // 2         commitment, codebook
  float* outEmb = out + 16842754;      // 262144    new_embedding
  float* outCS = out + 17104898;       // 1024      new_cluster_size
  float* outW = out + 17105922;        // 262144    new_ema_w

  hipMemsetAsync(counts, 0, (size_t)(1024 + 262144 + 1) * sizeof(float), stream);

  esq_kernel<<<KN / 4, 256, 0, stream>>>(emb, eSq);
  argmin_kernel<<<NV / 64, 256, 0, stream>>>(x, emb, eSq, idxBuf);
  gather_kernel<<<NV / 4, 256, 0, stream>>>(x, emb, idxBuf, outQ, outCodes,
                                            counts, dw, sse);
  finalize1<<<1, 1024, 0, stream>>>(ema_cs, counts, sse, norm, outCS, outLoss);
  finalize2<<<KN * DD / 256, 256, 0, stream>>>(ema_w, dw, norm, outEmb, outW);
}

// Round 2
// 925.444 us; speedup vs baseline: 1.7148x; 1.7148x over previous
//
#include <hip/hip_runtime.h>

// Problem constants
#define NV 65536     // flattened vectors (64*32*32)
#define KN 1024      // codebook size
#define DD 256       // embedding dim
#define DECAY_F 0.99f
#define OMD_F (1.0f - 0.99f)
#define EPS_F 1e-5f
#define CHUNK 8192   // idx chunk per LDS pass in dw_kernel (32 KiB list)

// ---------------------------------------------------------------------------
// Kernel 1: eSq[k] = ||embedding[k]||^2. One wave per row (4 waves/block).
// ---------------------------------------------------------------------------
__global__ __launch_bounds__(256) void esq_kernel(const float* __restrict__ emb,
                                                  float* __restrict__ eSq) {
  const int lane = threadIdx.x & 63;
  const int row = blockIdx.x * 4 + (threadIdx.x >> 6);
  const float4 v = *(const float4*)(emb + row * DD + lane * 4);
  float s = v.x * v.x + v.y * v.y + v.z * v.z + v.w * v.w;
  #pragma unroll
  for (int off = 32; off > 0; off >>= 1) s += __shfl_down(s, off, 64);
  if (lane == 0) eSq[row] = s;
}

// ---------------------------------------------------------------------------
// Kernel 2: fused distance + argmin (fp32 VALU GEMM).
// Block: 256 threads handles 64 n-rows. k loop in 4 chunks of 256.
// dist = ||e||^2 - 2 x.e  (||x||^2 constant per n, irrelevant for argmin).
// First-index tie-break to match jnp.argmin.
// ---------------------------------------------------------------------------
__global__ __launch_bounds__(256) void argmin_kernel(
    const float* __restrict__ x, const float* __restrict__ emb,
    const float* __restrict__ eSq, int* __restrict__ idxOut) {
  __shared__ float xs[16][64];    // [d][n]   4 KiB
  __shared__ float es[16][256];   // [d][k]  16 KiB
  __shared__ float sdist[64][16]; //          4 KiB
  __shared__ int   sidx[64][16];  //          4 KiB

  const int tid = threadIdx.x;
  const int tx = tid & 15;
  const int ty = tid >> 4;
  const int nBase = blockIdx.x * 64;

  const int ln = tid >> 2;        // 0..63
  const int ld = (tid & 3) * 4;   // 0,4,8,12

  float bestD[4];
  int bestK[4];
  #pragma unroll
  for (int i = 0; i < 4; i++) { bestD[i] = 3.4e38f; bestK[i] = 0; }

  for (int kc = 0; kc < 4; kc++) {
    float acc[4][16];
    #pragma unroll
    for (int i = 0; i < 4; i++)
      #pragma unroll
      for (int j = 0; j < 16; j++) acc[i][j] = 0.0f;

    for (int dc = 0; dc < 16; dc++) {
      const int d0 = dc * 16;
      const float4 xv = *(const float4*)(x + (nBase + ln) * DD + d0 + ld);
      float4 ev[4];
      #pragma unroll
      for (int p = 0; p < 4; p++)
        ev[p] = *(const float4*)(emb + (kc * 256 + p * 64 + ln) * DD + d0 + ld);

      __syncthreads();
      {
        float xa[4] = {xv.x, xv.y, xv.z, xv.w};
        #pragma unroll
        for (int j = 0; j < 4; j++) xs[ld + j][ln] = xa[j];
        #pragma unroll
        for (int p = 0; p < 4; p++) {
          float ea[4] = {ev[p].x, ev[p].y, ev[p].z, ev[p].w};
          #pragma unroll
          for (int j = 0; j < 4; j++) es[ld + j][p * 64 + ln] = ea[j];
        }
      }
      __syncthreads();

      #pragma unroll
      for (int d = 0; d < 16; d++) {
        const float4 xr = *(const float4*)&xs[d][ty * 4];
        const float4 e0 = *(const float4*)&es[d][tx * 16 + 0];
        const float4 e1 = *(const float4*)&es[d][tx * 16 + 4];
        const float4 e2 = *(const float4*)&es[d][tx * 16 + 8];
        const float4 e3 = *(const float4*)&es[d][tx * 16 + 12];
        const float xa[4] = {xr.x, xr.y, xr.z, xr.w};
        const float eb[16] = {e0.x, e0.y, e0.z, e0.w, e1.x, e1.y, e1.z, e1.w,
                              e2.x, e2.y, e2.z, e2.w, e3.x, e3.y, e3.z, e3.w};
        #pragma unroll
        for (int i = 0; i < 4; i++)
          #pragma unroll
          for (int j = 0; j < 16; j++) acc[i][j] += xa[i] * eb[j];
      }
    }

    #pragma unroll
    for (int j = 0; j < 16; j++) {
      const int k = kc * 256 + tx * 16 + j;
      const float es2 = eSq[k];
      #pragma unroll
      for (int i = 0; i < 4; i++) {
        const float dist = es2 - 2.0f * acc[i][j];
        if (dist < bestD[i]) { bestD[i] = dist; bestK[i] = k; }
      }
    }
  }

  __syncthreads();
  #pragma unroll
  for (int i = 0; i < 4; i++) {
    sdist[ty * 4 + i][tx] = bestD[i];
    sidx[ty * 4 + i][tx] = bestK[i];
  }
  __syncthreads();
  if (tid < 64) {
    float bd = sdist[tid][0];
    int bk = sidx[tid][0];
    #pragma unroll
    for (int t = 1; t < 16; t++) {
      const float d = sdist[tid][t];
      const int k2 = sidx[tid][t];
      if (d < bd || (d == bd && k2 < bk)) { bd = d; bk = k2; }
    }
    idxOut[nBase + tid] = bk;
  }
}

// ---------------------------------------------------------------------------
// Kernel 3: gather quantized, codes, SSE partials. One wave per vector.
// No dw/counts atomics here anymore; SSE goes to 256 slots (low contention).
// ---------------------------------------------------------------------------
__global__ __launch_bounds__(256) void gather_kernel(
    const float* __restrict__ x, const float* __restrict__ emb,
    const int* __restrict__ idx, float* __restrict__ outQ,
    float* __restrict__ outCodes, float* __restrict__ sseSlots) {
  const int lane = threadIdx.x & 63;
  const int n = blockIdx.x * 4 + (threadIdx.x >> 6);
  const int k = idx[n];

  const float4 xv = *(const float4*)(x + n * DD + lane * 4);
  const float4 ev = *(const float4*)(emb + k * DD + lane * 4);
  *(float4*)(outQ + n * DD + lane * 4) = ev;

  const float d0 = ev.x - xv.x, d1 = ev.y - xv.y, d2 = ev.z - xv.z, d3 = ev.w - xv.w;
  float s = d0 * d0 + d1 * d1 + d2 * d2 + d3 * d3;

  #pragma unroll
  for (int off = 32; off > 0; off >>= 1) s += __shfl_down(s, off, 64);
  if (lane == 0) {
    atomicAdd(&sseSlots[n & 255], s);
    outCodes[n] = (float)k;
  }
}

// ---------------------------------------------------------------------------
// Kernel 4: dw[k] = sum of x rows with idx==k, plus counts[k]. Atomic-free
// (only block-local LDS counter atomics). One block per code.
// idx is 256 KB -> L2-resident across all 1024 blocks' scans.
// ---------------------------------------------------------------------------
__global__ __launch_bounds__(256) void dw_kernel(
    const float* __restrict__ x, const int* __restrict__ idx,
    float* __restrict__ dw, float* __restrict__ counts) {
  const int k = blockIdx.x;
  const int d = threadIdx.x;
  __shared__ int list[CHUNK];
  __shared__ int cnt;

  float acc = 0.0f;
  int total = 0;

  for (int base = 0; base < NV; base += CHUNK) {
    if (d == 0) cnt = 0;
    __syncthreads();
    #pragma unroll 4
    for (int n = base + d; n < base + CHUNK; n += 256) {
      if (idx[n] == k) {
        const int p = atomicAdd(&cnt, 1);
        list[p] = n;
      }
    }
    __syncthreads();
    const int c = cnt;
    int i = 0;
    for (; i + 3 < c; i += 4) {
      const float a0 = x[list[i + 0] * DD + d];
      const float a1 = x[list[i + 1] * DD + d];
      const float a2 = x[list[i + 2] * DD + d];
      const float a3 = x[list[i + 3] * DD + d];
      acc += (a0 + a1) + (a2 + a3);
    }
    for (; i < c; i++) acc += x[list[i] * DD + d];
    total += c;
    __syncthreads();
  }

  dw[k * DD + d] = acc;
  if (d == 0) counts[k] = (float)total;
}

// ---------------------------------------------------------------------------
// Kernel 5a: new_cluster_size, n-sum, normalized, losses. Single 1024 block.
// ---------------------------------------------------------------------------
__global__ __launch_bounds__(1024) void finalize1(
    const float* __restrict__ ema_cs, const float* __restrict__ counts,
    const float* __restrict__ sseSlots, float* __restrict__ norm,
    float* __restrict__ outCS, float* __restrict__ outLoss) {
  __shared__ float red[1024];
  const int t = threadIdx.x;
  const float ncs = DECAY_F * ema_cs[t] + OMD_F * counts[t];
  outCS[t] = ncs;
  red[t] = ncs;
  __syncthreads();
  #pragma unroll
  for (int s = 512; s > 0; s >>= 1) {
    if (t < s) red[t] += red[t + s];
    __syncthreads();
  }
  const float n = red[0];
  __syncthreads();
  norm[t] = (ncs + EPS_F) / (n + (float)KN * EPS_F) * n;

  // SSE total from 256 slots
  red[t] = (t < 256) ? sseSlots[t] : 0.0f;
  __syncthreads();
  #pragma unroll
  for (int s = 512; s > 0; s >>= 1) {
    if (t < s) red[t] += red[t + s];
    __syncthreads();
  }
  if (t == 0) {
    const float mse = red[0] * (1.0f / 16777216.0f);
    outLoss[0] = 0.25f * mse;  // commitment
    outLoss[1] = mse;          // codebook
  }
}

// ---------------------------------------------------------------------------
// Kernel 5b: new_ema_w and new_embedding.
// ---------------------------------------------------------------------------
__global__ __launch_bounds__(256) void finalize2(
    const float* __restrict__ ema_w, const float* __restrict__ dw,
    const float* __restrict__ norm, float* __restrict__ outEmb,
    float* __restrict__ outW) {
  const int i = blockIdx.x * 256 + threadIdx.x;  // 0..262143
  const float nw = DECAY_F * ema_w[i] + OMD_F * dw[i];
  outW[i] = nw;
  outEmb[i] = nw / norm[i >> 8];
}

// ---------------------------------------------------------------------------
extern "C" void kernel_launch(void* const* d_in, const int* in_sizes, int n_in,
                              void* d_out, int out_size, void* d_ws, size_t ws_size,
                              hipStream_t stream) {
  const float* x = (const float*)d_in[0];        // [65536, 256]
  const float* emb = (const float*)d_in[1];      // [1024, 256]
  const float* ema_cs = (const float*)d_in[2];   // [1024]
  const float* ema_w = (const float*)d_in[3];    // [1024, 256]
  float* out = (float*)d_out;
  float* ws = (float*)d_ws;

  // workspace layout (float offsets)
  float* eSq = ws + 0;                  // 1024
  int* idxBuf = (int*)(ws + 1024);      // 65536 ints
  float* sseSlots = ws + 66560;         // 256  (needs zeroing)
  float* counts = ws + 66816;           // 1024 (written by dw_kernel)
  float* dw = ws + 67840;               // 262144 (written by dw_kernel)
  float* norm = ws + 329984;            // 1024

  // output layout (return-order flat, all fp32)
  float* outQ = out;                    // 16777216  quantized_st
  float* outCodes = out + 16777216;     // 65536     codes (as float)
  float* outLoss = out + 16842752;      // 2         commitment, codebook
  float* outEmb = out + 16842754;       // 262144    new_embedding
  float* outCS = out + 17104898;        // 1024      new_cluster_size
  float* outW = out + 17105922;         // 262144    new_ema_w

  hipMemsetAsync(sseSlots, 0, 256 * sizeof(float), stream);

  esq_kernel<<<KN / 4, 256, 0, stream>>>(emb, eSq);
  argmin_kernel<<<NV / 64, 256, 0, stream>>>(x, emb, eSq, idxBuf);
  gather_kernel<<<NV / 4, 256, 0, stream>>>(x, emb, idxBuf, outQ, outCodes,
                                            sseSlots);
  dw_kernel<<<KN, 256, 0, stream>>>(x, idxBuf, dw, counts);
  finalize1<<<1, 1024, 0, stream>>>(ema_cs, counts, sseSlots, norm, outCS,
                                    outLoss);
  finalize2<<<KN * DD / 256, 256, 0, stream>>>(ema_w, dw, norm, outEmb, outW);
}

// Round 3
// 820.225 us; speedup vs baseline: 1.9348x; 1.1283x over previous
//
#include <hip/hip_runtime.h>

// Problem constants
#define NV 65536     // flattened vectors (64*32*32)
#define KN 1024      // codebook size
#define DD 256       // embedding dim
#define DECAY_F 0.99f
#define OMD_F (1.0f - 0.99f)
#define EPS_F 1e-5f
#define CHUNK 8192   // idx chunk per LDS pass in dw_kernel (32 KiB list)

typedef __attribute__((ext_vector_type(8))) short short8;
typedef __attribute__((ext_vector_type(16))) float f32x16;

// ---------------------------------------------------------------------------
// bf16 split helpers (RTNE)
// ---------------------------------------------------------------------------
__device__ __forceinline__ void bf16_split(float v, short& hi, short& lo) {
  unsigned u = __float_as_uint(v);
  unsigned hr = (u + 0x7FFFu + ((u >> 16) & 1u)) >> 16;
  float hf = __uint_as_float(hr << 16);
  float rem = v - hf;
  unsigned u2 = __float_as_uint(rem);
  unsigned lr = (u2 + 0x7FFFu + ((u2 >> 16) & 1u)) >> 16;
  hi = (short)hr;
  lo = (short)lr;
}

// ---------------------------------------------------------------------------
// Kernel 0a: split x into x_hi/x_lo bf16 arrays (same [N][D] layout).
// ---------------------------------------------------------------------------
__global__ __launch_bounds__(256) void split_x(const float* __restrict__ x,
                                               short* __restrict__ xhi,
                                               short* __restrict__ xlo) {
  const int i = (blockIdx.x * 256 + threadIdx.x) * 8;
  float v[8];
  *(float4*)(v + 0) = *(const float4*)(x + i);
  *(float4*)(v + 4) = *(const float4*)(x + i + 4);
  short8 h, l;
  #pragma unroll
  for (int j = 0; j < 8; j++) {
    short hh, ll;
    bf16_split(v[j], hh, ll);
    h[j] = hh; l[j] = ll;
  }
  *(short8*)(xhi + i) = h;
  *(short8*)(xlo + i) = l;
}

// ---------------------------------------------------------------------------
// Kernel 0b: split e into the MFMA-staging tiled layout:
//   eT[cc(8)][dc(4)] tile of 16384 shorts: [h(2)][dblock(8)][code(128)][8]
// where global code = cc*128+code, global d = dc*64 + dblock*8 + j.
// ---------------------------------------------------------------------------
__global__ __launch_bounds__(256) void prep_e(const float* __restrict__ emb,
                                              short* __restrict__ eT) {
  const int b = blockIdx.x;   // 0..31 = cc*4 + dc
  const int cc = b >> 2, dc = b & 3;
  const int t = threadIdx.x;
  const int code = t >> 1;    // 0..127
  const int dhalf = t & 1;    // 0/1 -> d offset 0/32
  const float* src = emb + (cc * 128 + code) * 256 + dc * 64 + dhalf * 32;
  short* tile = eT + b * 16384;
  #pragma unroll
  for (int g = 0; g < 4; g++) {
    float v[8];
    *(float4*)(v + 0) = *(const float4*)(src + g * 8);
    *(float4*)(v + 4) = *(const float4*)(src + g * 8 + 4);
    short8 h, l;
    #pragma unroll
    for (int j = 0; j < 8; j++) {
      short hh, ll;
      bf16_split(v[j], hh, ll);
      h[j] = hh; l[j] = ll;
    }
    const int db = dhalf * 4 + g;
    *(short8*)(tile + ((0 * 8 + db) * 128 + code) * 8) = h;
    *(short8*)(tile + ((1 * 8 + db) * 128 + code) * 8) = l;
  }
}

// ---------------------------------------------------------------------------
// Kernel 1: eSq[k] = ||embedding[k]||^2 (fp32). One wave per row.
// ---------------------------------------------------------------------------
__global__ __launch_bounds__(256) void esq_kernel(const float* __restrict__ emb,
                                                  float* __restrict__ eSq) {
  const int lane = threadIdx.x & 63;
  const int row = blockIdx.x * 4 + (threadIdx.x >> 6);
  const float4 v = *(const float4*)(emb + row * DD + lane * 4);
  float s = v.x * v.x + v.y * v.y + v.z * v.z + v.w * v.w;
  #pragma unroll
  for (int off = 32; off > 0; off >>= 1) s += __shfl_down(s, off, 64);
  if (lane == 0) eSq[row] = s;
}

// ---------------------------------------------------------------------------
// Kernel 2: MFMA distance + top-2 argmin candidates.
// Block = 256 threads = 4 waves; block covers 256 queries (wave: 64 q as two
// 32-row A tiles). Codes in 8 chunks of 128 (4 B tiles of 32).
// dot = x_hi*e_hi + x_hi*e_lo + x_lo*e_hi  (3 MFMAs, one accumulator).
// dist = ||e||^2 - 2 dot. Fold via LDS transpose: thread t owns query t.
// ---------------------------------------------------------------------------
__global__ __launch_bounds__(256, 2) void argmin_mfma(
    const short* __restrict__ xhi, const short* __restrict__ xlo,
    const short* __restrict__ eT, const float* __restrict__ eSq,
    int2* __restrict__ cand) {
  __shared__ short eS[16384];          // 32 KiB staged e tile (hi+lo)
  __shared__ float distBuf[256 * 33];  // 33 KiB transpose buffer (+1 pad)
  __shared__ float eSqS[1024];

  const int tid = threadIdx.x;
  const int lane = tid & 63;
  const int wid = tid >> 6;
  const int l31 = lane & 31;
  const int lh = lane >> 5;
  const int qBaseBlk = blockIdx.x * 256;

  // stage eSq once
  *(float4*)(eSqS + tid * 4) = *(const float4*)(eSq + tid * 4);

  float b1d = 3.4e38f, b2d = 3.4e38f;
  int b1k = 0, b2k = 1;

  const int qA = qBaseBlk + wid * 64 + l31;        // A tile 0 row
  const int qB = qA + 32;                          // A tile 1 row

  for (int cc = 0; cc < 8; cc++) {
    f32x16 zero;
    #pragma unroll
    for (int i = 0; i < 16; i++) zero[i] = 0.0f;
    f32x16 acc[2][4];
    #pragma unroll
    for (int t = 0; t < 2; t++)
      #pragma unroll
      for (int ct = 0; ct < 4; ct++) acc[t][ct] = zero;

    for (int dc = 0; dc < 4; dc++) {
      __syncthreads();  // prev eS reads / prev fold reads complete
      {
        const char* src = (const char*)(eT + (cc * 4 + dc) * 16384);
        char* dst = (char*)eS;
        #pragma unroll
        for (int i = 0; i < 8; i++) {
          const int off = i * 4096 + tid * 16;
          *(float4*)(dst + off) = *(const float4*)(src + off);
        }
      }
      __syncthreads();

      #pragma unroll
      for (int ks = 0; ks < 4; ks++) {
        const int d = dc * 64 + ks * 16 + lh * 8;
        const short8 ahi0 = *(const short8*)(xhi + qA * DD + d);
        const short8 alo0 = *(const short8*)(xlo + qA * DD + d);
        const short8 ahi1 = *(const short8*)(xhi + qB * DD + d);
        const short8 alo1 = *(const short8*)(xlo + qB * DD + d);
        const int dblock = ks * 2 + lh;
        #pragma unroll
        for (int ct = 0; ct < 4; ct++) {
          const int cL = ct * 32 + l31;
          const short8 bhi = *(const short8*)(eS + (dblock * 128 + cL) * 8);
          const short8 blo = *(const short8*)(eS + ((8 + dblock) * 128 + cL) * 8);
          acc[0][ct] = __builtin_amdgcn_mfma_f32_32x32x16_bf16(ahi0, bhi, acc[0][ct], 0, 0, 0);
          acc[0][ct] = __builtin_amdgcn_mfma_f32_32x32x16_bf16(ahi0, blo, acc[0][ct], 0, 0, 0);
          acc[0][ct] = __builtin_amdgcn_mfma_f32_32x32x16_bf16(alo0, bhi, acc[0][ct], 0, 0, 0);
          acc[1][ct] = __builtin_amdgcn_mfma_f32_32x32x16_bf16(ahi1, bhi, acc[1][ct], 0, 0, 0);
          acc[1][ct] = __builtin_amdgcn_mfma_f32_32x32x16_bf16(ahi1, blo, acc[1][ct], 0, 0, 0);
          acc[1][ct] = __builtin_amdgcn_mfma_f32_32x32x16_bf16(alo1, bhi, acc[1][ct], 0, 0, 0);
        }
      }
    }

    // fold: per 32-code tile, transpose through LDS, thread t owns query t
    #pragma unroll 1
    for (int ct = 0; ct < 4; ct++) {
      __syncthreads();
      #pragma unroll
      for (int t = 0; t < 2; t++) {
        #pragma unroll
        for (int r = 0; r < 16; r++) {
          const int row = (r & 3) + 8 * (r >> 2) + 4 * lh;
          distBuf[(wid * 64 + t * 32 + row) * 33 + l31] = acc[t][ct][r];
        }
      }
      __syncthreads();
      const int kb = cc * 128 + ct * 32;
      #pragma unroll
      for (int c = 0; c < 32; c++) {
        const float s = distBuf[tid * 33 + c];
        const float dd = eSqS[kb + c] - 2.0f * s;
        const int k = kb + c;
        if (dd < b1d) { b2d = b1d; b2k = b1k; b1d = dd; b1k = k; }
        else if (dd < b2d) { b2d = dd; b2k = k; }
      }
    }
  }

  cand[qBaseBlk + tid] = make_int2(b1k, b2k);
}

// ---------------------------------------------------------------------------
// Kernel 3: exact fp32 rescue of the 2 candidates + gather + codes + SSE.
// One wave per query.
// ---------------------------------------------------------------------------
__global__ __launch_bounds__(256) void gather_rescue(
    const float* __restrict__ x, const float* __restrict__ emb,
    const int2* __restrict__ cand, float* __restrict__ outQ,
    float* __restrict__ outCodes, int* __restrict__ idxFinal,
    float* __restrict__ sseSlots) {
  const int lane = threadIdx.x & 63;
  const int n = blockIdx.x * 4 + (threadIdx.x >> 6);
  const int2 kk = cand[n];

  const float4 xv = *(const float4*)(x + n * DD + lane * 4);
  const float4 e1 = *(const float4*)(emb + kk.x * DD + lane * 4);
  const float4 e2 = *(const float4*)(emb + kk.y * DD + lane * 4);

  // per-lane partials of (||e||^2 - 2 x.e)
  float p1 = e1.x * (e1.x - 2.0f * xv.x) + e1.y * (e1.y - 2.0f * xv.y) +
             e1.z * (e1.z - 2.0f * xv.z) + e1.w * (e1.w - 2.0f * xv.w);
  float p2 = e2.x * (e2.x - 2.0f * xv.x) + e2.y * (e2.y - 2.0f * xv.y) +
             e2.z * (e2.z - 2.0f * xv.z) + e2.w * (e2.w - 2.0f * xv.w);
  #pragma unroll
  for (int m = 32; m > 0; m >>= 1) {
    p1 += __shfl_xor(p1, m, 64);
    p2 += __shfl_xor(p2, m, 64);
  }
  const bool pick2 = (p2 < p1) || (p2 == p1 && kk.y < kk.x);
  const int ksel = pick2 ? kk.y : kk.x;
  const float4 ev = pick2 ? e2 : e1;

  *(float4*)(outQ + n * DD + lane * 4) = ev;

  const float d0 = ev.x - xv.x, d1 = ev.y - xv.y, d2 = ev.z - xv.z,
              d3 = ev.w - xv.w;
  float s = d0 * d0 + d1 * d1 + d2 * d2 + d3 * d3;
  #pragma unroll
  for (int m = 32; m > 0; m >>= 1) s += __shfl_down(s, m, 64);
  if (lane == 0) {
    atomicAdd(&sseSlots[n & 255], s);
    idxFinal[n] = ksel;
    outCodes[n] = (float)ksel;
  }
}

// ---------------------------------------------------------------------------
// Kernel 4: dw[k] = sum of x rows with idx==k, plus counts[k]. One block/code.
// ---------------------------------------------------------------------------
__global__ __launch_bounds__(256) void dw_kernel(
    const float* __restrict__ x, const int* __restrict__ idx,
    float* __restrict__ dw, float* __restrict__ counts) {
  const int k = blockIdx.x;
  const int d = threadIdx.x;
  __shared__ int list[CHUNK];
  __shared__ int cnt;

  float acc = 0.0f;
  int total = 0;

  for (int base = 0; base < NV; base += CHUNK) {
    if (d == 0) cnt = 0;
    __syncthreads();
    #pragma unroll 4
    for (int n = base + d; n < base + CHUNK; n += 256) {
      if (idx[n] == k) {
        const int p = atomicAdd(&cnt, 1);
        list[p] = n;
      }
    }
    __syncthreads();
    const int c = cnt;
    int i = 0;
    for (; i + 3 < c; i += 4) {
      const float a0 = x[list[i + 0] * DD + d];
      const float a1 = x[list[i + 1] * DD + d];
      const float a2 = x[list[i + 2] * DD + d];
      const float a3 = x[list[i + 3] * DD + d];
      acc += (a0 + a1) + (a2 + a3);
    }
    for (; i < c; i++) acc += x[list[i] * DD + d];
    total += c;
    __syncthreads();
  }

  dw[k * DD + d] = acc;
  if (d == 0) counts[k] = (float)total;
}

// ---------------------------------------------------------------------------
// Kernel 5a: new_cluster_size, n-sum, normalized, losses. Single 1024 block.
// ---------------------------------------------------------------------------
__global__ __launch_bounds__(1024) void finalize1(
    const float* __restrict__ ema_cs, const float* __restrict__ counts,
    const float* __restrict__ sseSlots, float* __restrict__ norm,
    float* __restrict__ outCS, float* __restrict__ outLoss) {
  __shared__ float red[1024];
  const int t = threadIdx.x;
  const float ncs = DECAY_F * ema_cs[t] + OMD_F * counts[t];
  outCS[t] = ncs;
  red[t] = ncs;
  __syncthreads();
  #pragma unroll
  for (int s = 512; s > 0; s >>= 1) {
    if (t < s) red[t] += red[t + s];
    __syncthreads();
  }
  const float n = red[0];
  __syncthreads();
  norm[t] = (ncs + EPS_F) / (n + (float)KN * EPS_F) * n;

  red[t] = (t < 256) ? sseSlots[t] : 0.0f;
  __syncthreads();
  #pragma unroll
  for (int s = 512; s > 0; s >>= 1) {
    if (t < s) red[t] += red[t + s];
    __syncthreads();
  }
  if (t == 0) {
    const float mse = red[0] * (1.0f / 16777216.0f);
    outLoss[0] = 0.25f * mse;  // commitment
    outLoss[1] = mse;          // codebook
  }
}

// ---------------------------------------------------------------------------
// Kernel 5b: new_ema_w and new_embedding.
// ---------------------------------------------------------------------------
__global__ __launch_bounds__(256) void finalize2(
    const float* __restrict__ ema_w, const float* __restrict__ dw,
    const float* __restrict__ norm, float* __restrict__ outEmb,
    float* __restrict__ outW) {
  const int i = blockIdx.x * 256 + threadIdx.x;  // 0..262143
  const float nw = DECAY_F * ema_w[i] + OMD_F * dw[i];
  outW[i] = nw;
  outEmb[i] = nw / norm[i >> 8];
}

// ---------------------------------------------------------------------------
extern "C" void kernel_launch(void* const* d_in, const int* in_sizes, int n_in,
                              void* d_out, int out_size, void* d_ws, size_t ws_size,
                              hipStream_t stream) {
  const float* x = (const float*)d_in[0];        // [65536, 256]
  const float* emb = (const float*)d_in[1];      // [1024, 256]
  const float* ema_cs = (const float*)d_in[2];   // [1024]
  const float* ema_w = (const float*)d_in[3];    // [1024, 256]
  float* out = (float*)d_out;
  float* ws = (float*)d_ws;

  // --- workspace (float offsets); footprint ~1.3 MB (same as proven R2) ---
  float* eSq = ws + 0;                   // 1024
  float* sseSlots = ws + 1024;           // 256 (memset)
  float* counts = ws + 1280;             // 1024
  float* dw = ws + 2304;                 // 262144
  float* norm = ws + 264448;             // 1024
  int* idxFinal = (int*)(ws + 265472);   // 65536 ints

  // --- d_out doubles as phase-1 scratch (regions dead until later writes) ---
  // phase-1: xhi/xlo occupy the outQ region; eT + cand the tail region.
  short* xhi = (short*)out;                     // 16.7M bf16 = out[0..8388608)
  short* xlo = (short*)(out + 8388608);         // out[8388608..16777216)
  short* eT = (short*)(out + 16777216);         // 524288 shorts = 262144 floats
  int2* cand = (int2*)(out + 17039360);         // 65536 int2 = 131072 floats

  // --- final output layout (return-order flat, fp32) ---
  float* outQ = out;                    // 16777216  quantized_st
  float* outCodes = out + 16777216;     // 65536     codes (as float)
  float* outLoss = out + 16842752;      // 2         commitment, codebook
  float* outEmb = out + 16842754;       // 262144    new_embedding
  float* outCS = out + 17104898;        // 1024      new_cluster_size
  float* outW = out + 17105922;         // 262144    new_ema_w

  hipMemsetAsync(sseSlots, 0, 256 * sizeof(float), stream);

  split_x<<<NV * DD / (256 * 8), 256, 0, stream>>>(x, xhi, xlo);
  prep_e<<<32, 256, 0, stream>>>(emb, eT);
  esq_kernel<<<KN / 4, 256, 0, stream>>>(emb, eSq);
  argmin_mfma<<<NV / 256, 256, 0, stream>>>(xhi, xlo, eT, eSq, cand);
  gather_rescue<<<NV / 4, 256, 0, stream>>>(x, emb, cand, outQ, outCodes,
                                            idxFinal, sseSlots);
  dw_kernel<<<KN, 256, 0, stream>>>(x, idxFinal, dw, counts);
  finalize1<<<1, 1024, 0, stream>>>(ema_cs, counts, sseSlots, norm, outCS,
                                    outLoss);
  finalize2<<<KN * DD / 256, 256, 0, stream>>>(ema_w, dw, norm, outEmb, outW);
}

// Round 5
// 496.834 us; speedup vs baseline: 3.1941x; 1.6509x over previous
//
#include <hip/hip_runtime.h>

// Problem constants
#define NV 65536     // flattened vectors (64*32*32)
#define KN 1024      // codebook size
#define DD 256       // embedding dim
#define DECAY_F 0.99f
#define OMD_F (1.0f - 0.99f)
#define EPS_F 1e-5f
#define CHUNK 8192   // idx chunk per LDS pass in dw_kernel (32 KiB list)

typedef __attribute__((ext_vector_type(8))) short short8;
typedef __attribute__((ext_vector_type(16))) float f32x16;

// ---------------------------------------------------------------------------
// bf16 split helpers (RTNE)
// ---------------------------------------------------------------------------
__device__ __forceinline__ void bf16_split(float v, short& hi, short& lo) {
  unsigned u = __float_as_uint(v);
  unsigned hr = (u + 0x7FFFu + ((u >> 16) & 1u)) >> 16;
  float hf = __uint_as_float(hr << 16);
  float rem = v - hf;
  unsigned u2 = __float_as_uint(rem);
  unsigned lr = (u2 + 0x7FFFu + ((u2 >> 16) & 1u)) >> 16;
  hi = (short)hr;
  lo = (short)lr;
}

// ---------------------------------------------------------------------------
// Kernel 0a: split x into x_hi/x_lo bf16 arrays (same [N][D] layout).
// ---------------------------------------------------------------------------
__global__ __launch_bounds__(256) void split_x(const float* __restrict__ x,
                                               short* __restrict__ xhi,
                                               short* __restrict__ xlo) {
  const int i = (blockIdx.x * 256 + threadIdx.x) * 8;
  float v[8];
  *(float4*)(v + 0) = *(const float4*)(x + i);
  *(float4*)(v + 4) = *(const float4*)(x + i + 4);
  short8 h, l;
  #pragma unroll
  for (int j = 0; j < 8; j++) {
    short hh, ll;
    bf16_split(v[j], hh, ll);
    h[j] = hh; l[j] = ll;
  }
  *(short8*)(xhi + i) = h;
  *(short8*)(xlo + i) = l;
}

// ---------------------------------------------------------------------------
// Kernel 0b: split e into the MFMA-staging tiled layout.
// 32 tiles (cc 0..3, dc 0..7), each 16384 shorts:
//   [h(2)][db(4)][code(256)][8]   global code = cc*256+code, d = dc*32+db*8+j
// ---------------------------------------------------------------------------
__global__ __launch_bounds__(256) void prep_e(const float* __restrict__ emb,
                                              short* __restrict__ eT) {
  const int b = blockIdx.x;   // 0..31 = cc*8 + dc
  const int cc = b >> 3, dc = b & 7;
  const int c = threadIdx.x;  // code within chunk, 0..255
  const float* src = emb + (cc * 256 + c) * 256 + dc * 32;
  short* tile = eT + b * 16384;
  #pragma unroll
  for (int db = 0; db < 4; db++) {
    float v[8];
    *(float4*)(v + 0) = *(const float4*)(src + db * 8);
    *(float4*)(v + 4) = *(const float4*)(src + db * 8 + 4);
    short8 h, l;
    #pragma unroll
    for (int j = 0; j < 8; j++) {
      short hh, ll;
      bf16_split(v[j], hh, ll);
      h[j] = hh; l[j] = ll;
    }
    *(short8*)(tile + ((0 * 4 + db) * 256 + c) * 8) = h;
    *(short8*)(tile + ((1 * 4 + db) * 256 + c) * 8) = l;
  }
}

// ---------------------------------------------------------------------------
// Kernel 1: eSq[k] = ||embedding[k]||^2 (fp32). One wave per row.
// ---------------------------------------------------------------------------
__global__ __launch_bounds__(256) void esq_kernel(const float* __restrict__ emb,
                                                  float* __restrict__ eSq) {
  const int lane = threadIdx.x & 63;
  const int row = blockIdx.x * 4 + (threadIdx.x >> 6);
  const float4 v = *(const float4*)(emb + row * DD + lane * 4);
  float s = v.x * v.x + v.y * v.y + v.z * v.z + v.w * v.w;
  #pragma unroll
  for (int off = 32; off > 0; off >>= 1) s += __shfl_down(s, off, 64);
  if (lane == 0) eSq[row] = s;
}

// ---------------------------------------------------------------------------
// Kernel 2: MFMA distance + exact best-2 candidates.
// Block = 4 waves = 128 queries; wave = 32 q (1 A tile) x 256 codes (8 B
// tiles, acc[8] = 128 VGPRs). Codes in 4 chunks of 256; d in 8 chunks of 32.
// dot = x_hi*e_hi + x_hi*e_lo + x_lo*e_hi  (3 MFMAs, fp32 accum).
// LDS: 32 KB e-stage UNIONed with 67.6 KB fold buffer (disjoint lifetimes).
// R5 fix: __syncthreads() after eSqS staging (R4 read it pre-barrier: race).
// ---------------------------------------------------------------------------
__global__ __launch_bounds__(256, 2) void argmin_mfma(
    const short* __restrict__ xhi, const short* __restrict__ xlo,
    const short* __restrict__ eT, const float* __restrict__ eSq,
    int2* __restrict__ cand) {
  __shared__ __align__(16) char uS[67584];  // union: eS (32 KB) / db (66 KB)
  __shared__ float eSqS[1024];

  short* eS = (short*)uS;
  float2* dbAll = (float2*)uS;

  const int tid = threadIdx.x;
  const int lane = tid & 63;
  const int wid = tid >> 6;
  const int l31 = lane & 31;
  const int lh = lane >> 5;
  const int qBase = blockIdx.x * 128 + wid * 32;

  // stage eSq once (1024 floats)
  *(float4*)(eSqS + tid * 4) = *(const float4*)(eSq + tid * 4);
  __syncthreads();  // eSqS visible to all waves BEFORE first es2 read (R5 fix)

  float2* dbW = dbAll + wid * (64 * 33);

  float b1d = 3.4e38f, b2d = 3.4e38f;
  int b1k = 0, b2k = 1;

  const long qRow = (long)(qBase + l31) * DD;

  for (int cc = 0; cc < 4; cc++) {
    f32x16 acc[8];
    #pragma unroll
    for (int ct = 0; ct < 8; ct++)
      #pragma unroll
      for (int i = 0; i < 16; i++) acc[ct][i] = 0.0f;

    float es2[8];
    #pragma unroll
    for (int ct = 0; ct < 8; ct++) es2[ct] = eSqS[cc * 256 + ct * 32 + l31];

    for (int dc = 0; dc < 8; dc++) {
      __syncthreads();  // prior eS/db reads complete
      {
        const char* src = (const char*)(eT + (cc * 8 + dc) * 16384);
        #pragma unroll
        for (int i = 0; i < 8; i++) {
          const int off = i * 4096 + tid * 16;
          *(float4*)(uS + off) = *(const float4*)(src + off);
        }
      }
      __syncthreads();  // tile staged

      #pragma unroll
      for (int ks = 0; ks < 2; ks++) {
        const int d = dc * 32 + ks * 16 + lh * 8;
        const short8 ahi = *(const short8*)(xhi + qRow + d);
        const short8 alo = *(const short8*)(xlo + qRow + d);
        const int db = ks * 2 + lh;
        #pragma unroll
        for (int ct = 0; ct < 8; ct++) {
          const int cL = ct * 32 + l31;
          const short8 bhi = *(const short8*)(eS + ((0 * 4 + db) * 256 + cL) * 8);
          const short8 blo = *(const short8*)(eS + ((1 * 4 + db) * 256 + cL) * 8);
          acc[ct] = __builtin_amdgcn_mfma_f32_32x32x16_bf16(ahi, bhi, acc[ct], 0, 0, 0);
          acc[ct] = __builtin_amdgcn_mfma_f32_32x32x16_bf16(ahi, blo, acc[ct], 0, 0, 0);
          acc[ct] = __builtin_amdgcn_mfma_f32_32x32x16_bf16(alo, bhi, acc[ct], 0, 0, 0);
        }
      }
    }

    __syncthreads();  // all waves done reading eS; uS becomes fold buffer

    // per-(lane,reg): exact best2 over the 8 ct codes; transpose via LDS.
    // db layout per wave: float2 [cand(64)][query(32)+1pad]
    #pragma unroll
    for (int r = 0; r < 16; r++) {
      const int row = (r & 3) + 8 * (r >> 2) + 4 * lh;  // query row 0..31
      float cb1 = 3.4e38f, cb2 = 3.4e38f;
      int ck1 = 0, ck2 = 0;
      #pragma unroll
      for (int ct = 0; ct < 8; ct++) {
        const float dd = es2[ct] - 2.0f * acc[ct][r];
        const int k = cc * 256 + ct * 32 + l31;
        if (dd < cb1) { cb2 = cb1; ck2 = ck1; cb1 = dd; ck1 = k; }
        else if (dd < cb2) { cb2 = dd; ck2 = k; }
      }
      dbW[(l31 * 2 + 0) * 33 + row] = make_float2(cb1, __int_as_float(ck1));
      dbW[(l31 * 2 + 1) * 33 + row] = make_float2(cb2, __int_as_float(ck2));
    }
    __syncthreads();  // transpose visible (also keeps waves phase-aligned)

    // lane (l31, lh) folds candidates lh*32..lh*32+31 for query l31
    #pragma unroll
    for (int i = 0; i < 32; i++) {
      const float2 c = dbW[(lh * 32 + i) * 33 + l31];
      const float dd = c.x;
      const int k = __float_as_int(c.y);
      if (dd < b1d) { b2d = b1d; b2k = b1k; b1d = dd; b1k = k; }
      else if (dd < b2d) { b2d = dd; b2k = k; }
    }
  }

  // merge lane pairs (l, l+32): exact best2 of the union, k-tiebreak
  {
    const float p1d = __shfl_xor(b1d, 32, 64);
    const int p1k = __shfl_xor(b1k, 32, 64);
    const float p2d = __shfl_xor(b2d, 32, 64);
    const int p2k = __shfl_xor(b2k, 32, 64);
    if ((p1d < b1d) || (p1d == b1d && p1k < b1k)) {
      b2d = b1d; b2k = b1k; b1d = p1d; b1k = p1k;
    } else if ((p1d < b2d) || (p1d == b2d && p1k < b2k)) {
      b2d = p1d; b2k = p1k;
    }
    if ((p2d < b1d) || (p2d == b1d && p2k < b1k)) {
      b2d = b1d; b2k = b1k; b1d = p2d; b1k = p2k;
    } else if ((p2d < b2d) || (p2d == b2d && p2k < b2k)) {
      b2d = p2d; b2k = p2k;
    }
  }
  if (lh == 0) cand[qBase + l31] = make_int2(b1k, b2k);
}

// ---------------------------------------------------------------------------
// Kernel 3: exact fp32 rescue of the 2 candidates + gather + codes + SSE.
// One wave per query.
// ---------------------------------------------------------------------------
__global__ __launch_bounds__(256) void gather_rescue(
    const float* __restrict__ x, const float* __restrict__ emb,
    const int2* __restrict__ cand, float* __restrict__ outQ,
    float* __restrict__ outCodes, int* __restrict__ idxFinal,
    float* __restrict__ sseSlots) {
  const int lane = threadIdx.x & 63;
  const int n = blockIdx.x * 4 + (threadIdx.x >> 6);
  const int2 kk = cand[n];

  const float4 xv = *(const float4*)(x + n * DD + lane * 4);
  const float4 e1 = *(const float4*)(emb + kk.x * DD + lane * 4);
  const float4 e2 = *(const float4*)(emb + kk.y * DD + lane * 4);

  float p1 = e1.x * (e1.x - 2.0f * xv.x) + e1.y * (e1.y - 2.0f * xv.y) +
             e1.z * (e1.z - 2.0f * xv.z) + e1.w * (e1.w - 2.0f * xv.w);
  float p2 = e2.x * (e2.x - 2.0f * xv.x) + e2.y * (e2.y - 2.0f * xv.y) +
             e2.z * (e2.z - 2.0f * xv.z) + e2.w * (e2.w - 2.0f * xv.w);
  #pragma unroll
  for (int m = 32; m > 0; m >>= 1) {
    p1 += __shfl_xor(p1, m, 64);
    p2 += __shfl_xor(p2, m, 64);
  }
  const bool pick2 = (p2 < p1) || (p2 == p1 && kk.y < kk.x);
  const int ksel = pick2 ? kk.y : kk.x;
  const float4 ev = pick2 ? e2 : e1;

  *(float4*)(outQ + n * DD + lane * 4) = ev;

  const float d0 = ev.x - xv.x, d1 = ev.y - xv.y, d2 = ev.z - xv.z,
              d3 = ev.w - xv.w;
  float s = d0 * d0 + d1 * d1 + d2 * d2 + d3 * d3;
  #pragma unroll
  for (int m = 32; m > 0; m >>= 1) s += __shfl_down(s, m, 64);
  if (lane == 0) {
    atomicAdd(&sseSlots[n & 255], s);
    idxFinal[n] = ksel;
    outCodes[n] = (float)ksel;
  }
}

// ---------------------------------------------------------------------------
// Kernel 4: dw[k] = sum of x rows with idx==k, plus counts[k]. One block/code.
// ---------------------------------------------------------------------------
__global__ __launch_bounds__(256) void dw_kernel(
    const float* __restrict__ x, const int* __restrict__ idx,
    float* __restrict__ dw, float* __restrict__ counts) {
  const int k = blockIdx.x;
  const int d = threadIdx.x;
  __shared__ int list[CHUNK];
  __shared__ int cnt;

  float acc = 0.0f;
  int total = 0;

  for (int base = 0; base < NV; base += CHUNK) {
    if (d == 0) cnt = 0;
    __syncthreads();
    #pragma unroll 4
    for (int n = base + d; n < base + CHUNK; n += 256) {
      if (idx[n] == k) {
        const int p = atomicAdd(&cnt, 1);
        list[p] = n;
      }
    }
    __syncthreads();
    const int c = cnt;
    int i = 0;
    for (; i + 3 < c; i += 4) {
      const float a0 = x[list[i + 0] * DD + d];
      const float a1 = x[list[i + 1] * DD + d];
      const float a2 = x[list[i + 2] * DD + d];
      const float a3 = x[list[i + 3] * DD + d];
      acc += (a0 + a1) + (a2 + a3);
    }
    for (; i < c; i++) acc += x[list[i] * DD + d];
    total += c;
    __syncthreads();
  }

  dw[k * DD + d] = acc;
  if (d == 0) counts[k] = (float)total;
}

// ---------------------------------------------------------------------------
// Kernel 5a: new_cluster_size, n-sum, normalized, losses. Single 1024 block.
// ---------------------------------------------------------------------------
__global__ __launch_bounds__(1024) void finalize1(
    const float* __restrict__ ema_cs, const float* __restrict__ counts,
    const float* __restrict__ sseSlots, float* __restrict__ norm,
    float* __restrict__ outCS, float* __restrict__ outLoss) {
  __shared__ float red[1024];
  const int t = threadIdx.x;
  const float ncs = DECAY_F * ema_cs[t] + OMD_F * counts[t];
  outCS[t] = ncs;
  red[t] = ncs;
  __syncthreads();
  #pragma unroll
  for (int s = 512; s > 0; s >>= 1) {
    if (t < s) red[t] += red[t + s];
    __syncthreads();
  }
  const float n = red[0];
  __syncthreads();
  norm[t] = (ncs + EPS_F) / (n + (float)KN * EPS_F) * n;

  red[t] = (t < 256) ? sseSlots[t] : 0.0f;
  __syncthreads();
  #pragma unroll
  for (int s = 512; s > 0; s >>= 1) {
    if (t < s) red[t] += red[t + s];
    __syncthreads();
  }
  if (t == 0) {
    const float mse = red[0] * (1.0f / 16777216.0f);
    outLoss[0] = 0.25f * mse;  // commitment
    outLoss[1] = mse;          // codebook
  }
}

// ---------------------------------------------------------------------------
// Kernel 5b: new_ema_w and new_embedding.
// ---------------------------------------------------------------------------
__global__ __launch_bounds__(256) void finalize2(
    const float* __restrict__ ema_w, const float* __restrict__ dw,
    const float* __restrict__ norm, float* __restrict__ outEmb,
    float* __restrict__ outW) {
  const int i = blockIdx.x * 256 + threadIdx.x;  // 0..262143
  const float nw = DECAY_F * ema_w[i] + OMD_F * dw[i];
  outW[i] = nw;
  outEmb[i] = nw / norm[i >> 8];
}

// ---------------------------------------------------------------------------
extern "C" void kernel_launch(void* const* d_in, const int* in_sizes, int n_in,
                              void* d_out, int out_size, void* d_ws, size_t ws_size,
                              hipStream_t stream) {
  const float* x = (const float*)d_in[0];        // [65536, 256]
  const float* emb = (const float*)d_in[1];      // [1024, 256]
  const float* ema_cs = (const float*)d_in[2];   // [1024]
  const float* ema_w = (const float*)d_in[3];    // [1024, 256]
  float* out = (float*)d_out;
  float* ws = (float*)d_ws;

  // --- workspace (float offsets) ---
  float* eSq = ws + 0;                   // 1024
  float* sseSlots = ws + 1024;           // 256 (memset)
  float* counts = ws + 1280;             // 1024
  float* dw = ws + 2304;                 // 262144
  float* norm = ws + 264448;             // 1024
  int* idxFinal = (int*)(ws + 265472);   // 65536 ints

  // --- d_out doubles as phase-1 scratch (stream-ordered lifetimes) ---
  short* xhi = (short*)out;                     // out[0..8388608)
  short* xlo = (short*)(out + 8388608);         // out[8388608..16777216)
  short* eT = (short*)(out + 16777216);         // 524288 shorts
  int2* cand = (int2*)(out + 17039360);         // 65536 int2

  // --- final output layout (return-order flat, fp32) ---
  float* outQ = out;                    // 16777216  quantized_st
  float* outCodes = out + 16777216;     // 65536     codes (as float)
  float* outLoss = out + 16842752;      // 2         commitment, codebook
  float* outEmb = out + 16842754;       // 262144    new_embedding
  float* outCS = out + 17104898;        // 1024      new_cluster_size
  float* outW = out + 17105922;         // 262144    new_ema_w

  hipMemsetAsync(sseSlots, 0, 256 * sizeof(float), stream);

  split_x<<<NV * DD / (256 * 8), 256, 0, stream>>>(x, xhi, xlo);
  prep_e<<<32, 256, 0, stream>>>(emb, eT);
  esq_kernel<<<KN / 4, 256, 0, stream>>>(emb, eSq);
  argmin_mfma<<<NV / 128, 256, 0, stream>>>(xhi, xlo, eT, eSq, cand);
  gather_rescue<<<NV / 4, 256, 0, stream>>>(x, emb, cand, outQ, outCodes,
                                            idxFinal, sseSlots);
  dw_kernel<<<KN, 256, 0, stream>>>(x, idxFinal, dw, counts);
  finalize1<<<1, 1024, 0, stream>>>(ema_cs, counts, sseSlots, norm, outCS,
                                    outLoss);
  finalize2<<<KN * DD / 256, 256, 0, stream>>>(ema_w, dw, norm, outEmb, outW);
}